// Round 7
// baseline (7309.598 us; speedup 1.0000x reference)
//
#include <hip/hip_runtime.h>
#include <math.h>

#define NTHR 512

// ---------------------------------------------------------------- uncached ops
__device__ __forceinline__ void st_uc(float* p, float v) {
    asm volatile("global_store_dword %0, %1, off sc0 sc1" :: "v"(p), "v"(v) : "memory");
}
__device__ __forceinline__ void st_uc_u(unsigned* p, unsigned v) {
    asm volatile("global_store_dword %0, %1, off sc0 sc1" :: "v"(p), "v"(v) : "memory");
}
__device__ __forceinline__ float4 ld_uc4_nw(const float4* p) {   // no wait; caller drains vmcnt
    float4 v;
    asm volatile("global_load_dwordx4 %0, %1, off sc0 sc1" : "=v"(v) : "v"(p) : "memory");
    return v;
}
// two scalar uncached loads, one wait
__device__ __forceinline__ void ld_uc2(const float* p0, const float* p1, float& r0, float& r1) {
    asm volatile("global_load_dword %0, %2, off sc0 sc1\n\t"
                 "global_load_dword %1, %3, off sc0 sc1\n\t"
                 "s_waitcnt vmcnt(0)"
                 : "=&v"(r0), "=&v"(r1) : "v"(p0), "v"(p1) : "memory");
}
// one wave polls all 64 slice tags (lanes 0..63 <-> tags 0..63, 4 cache lines)
__device__ __forceinline__ void spin_tags64(const unsigned* base, int L, unsigned target) {
    const unsigned* p = base + L;
    for (;;) {
        unsigned v;
        asm volatile("global_load_dword %0, %1, off sc0 sc1\n\ts_waitcnt vmcnt(0)"
                     : "=v"(v) : "v"(p) : "memory");
        if (!__any((int)(v < target))) return;
        __builtin_amdgcn_s_sleep(1);
    }
}

// ---------------------------------------------------------------- init
// h_buf: 2 slots x 32768 floats (both zeroed = h(-1)); tags: 4 bg x 128 uints.
__global__ void init_kernel(float* h_buf, unsigned* tags) {
    int i = blockIdx.x * blockDim.x + threadIdx.x;
    if (i < 65536) st_uc(h_buf + i, 0.0f);
    if (i < 512) st_uc_u(tags + i, 0u);
}

// ---------------------------------------------------------------- xb = x @ b
// Normal cached stores: the xb_gemm->scan dispatch boundary is a device-scope
// release (L2 writeback), so the scan's uncached LLC reads of XB are correct.
__global__ __launch_bounds__(256) void xb_gemm(const float* __restrict__ X,
                                               const float* __restrict__ Bw,
                                               float* __restrict__ XB) {
    __shared__ float xs[16][132];
    __shared__ float bs[16][132];
    const int bm = blockIdx.x >> 3;
    const int bn = blockIdx.x & 7;
    const int m0 = bm * 128, n0 = bn * 128;
    const int tid = threadIdx.x;
    const int tx = tid & 15, ty = tid >> 4;
    float acc[8][8];
#pragma unroll
    for (int i = 0; i < 8; ++i)
#pragma unroll
        for (int j = 0; j < 8; ++j) acc[i][j] = 0.f;

    for (int k0 = 0; k0 < 1024; k0 += 16) {
#pragma unroll
        for (int p = 0; p < 2; ++p) {
            int f = tid + p * 256;
            int m = f >> 2, kq = f & 3;
            float4 v = *(const float4*)&X[(size_t)(m0 + m) * 1024 + k0 + kq * 4];
            xs[kq * 4 + 0][m] = v.x; xs[kq * 4 + 1][m] = v.y;
            xs[kq * 4 + 2][m] = v.z; xs[kq * 4 + 3][m] = v.w;
        }
#pragma unroll
        for (int p = 0; p < 2; ++p) {
            int f = tid + p * 256;
            int k = f >> 5, n = (f & 31) * 4;
            float4 v = *(const float4*)&Bw[(size_t)(k0 + k) * 1024 + n0 + n];
            *(float4*)&bs[k][n] = v;
        }
        __syncthreads();
#pragma unroll
        for (int k = 0; k < 16; ++k) {
            float xv[8], bv[8];
            *(float4*)&xv[0] = *(const float4*)&xs[k][ty * 8];
            *(float4*)&xv[4] = *(const float4*)&xs[k][ty * 8 + 4];
            *(float4*)&bv[0] = *(const float4*)&bs[k][tx * 8];
            *(float4*)&bv[4] = *(const float4*)&bs[k][tx * 8 + 4];
#pragma unroll
            for (int i = 0; i < 8; ++i)
#pragma unroll
                for (int j = 0; j < 8; ++j) acc[i][j] += xv[i] * bv[j];
        }
        __syncthreads();
    }
#pragma unroll
    for (int i = 0; i < 8; ++i)
#pragma unroll
        for (int j = 0; j < 8; j += 4) {
            float4 v = make_float4(acc[i][j], acc[i][j + 1], acc[i][j + 2], acc[i][j + 3]);
            *(float4*)&XB[(size_t)(m0 + ty * 8 + i) * 1024 + n0 + tx * 8 + j] = v;
        }
}

// ---------------------------------------------------------------- persistent scan
// 256 WGs = 4 batch-groups (8 batches) x 64 col-slices (16 cols).
// Tag protocol (r4/r5, proven): per-slice monotonic tags, depth-2 ping-pong h/g.
// This round: single poll wave (w7) + syncthreads release; coalesced LDS staging
// (64B/thread) restored; scr (2KB) aliases stage buffer (guarded by sync order).
__global__ __launch_bounds__(NTHR, 1) void scan_kernel(
    const float* __restrict__ A, const float* __restrict__ CTm,
    float* __restrict__ XBH, float* __restrict__ h_buf, float* __restrict__ g_buf,
    float* __restrict__ ht_out, float* __restrict__ ct_out, unsigned* __restrict__ tags) {
    extern __shared__ float lds[];
    float* a_lf  = lds;                   // [16 cols][1024] col-major (64KB)
    float* ct_lf = lds + 16384;           // (64KB)
    float* hg_f  = lds + 32768;           // staging 8192 floats (32KB); scr aliases head
    float4* a_l4  = (float4*)a_lf;
    float4* ct_l4 = (float4*)ct_lf;
    float4* hg4   = (float4*)hg_f;
    float* scr = hg_f;                    // 512 floats

    const int wg = blockIdx.x;
    const int bg = wg >> 6;
    const int sg = wg & 63;
    const int c0wg = sg * 16;
    const int tid = threadIdx.x;
    unsigned* tagH = tags + (bg << 7);
    unsigned* tagG = tagH + 64;

    // ---- one-time weight preload: columns c0wg..c0wg+15, linear col-major ----
    {
        const int c = tid & 15, i0 = tid >> 4;
        for (int i = i0; i < 1024; i += 32) {
            a_lf[c * 1024 + i]  = A[(size_t)i * 1024 + c0wg + c];
            ct_lf[c * 1024 + i] = CTm[(size_t)i * 1024 + c0wg + c];
        }
    }

    const int L  = tid & 63;
    const int w  = tid >> 6;
    const int Lc = L & 7;
    const int Lb = (L >> 3) & 7;
    const int cg = w & 1, kq = w >> 1;

    int aIdx[8], hIdx[8];
#pragma unroll
    for (int c = 0; c < 8; ++c) aIdx[c] = (cg * 8 + (c ^ Lc)) * 256 + kq * 64 + L;
#pragma unroll
    for (int r = 0; r < 8; ++r) hIdx[r] = (r ^ Lb) * 256 + kq * 64 + L;

    // epilogue lane mapping (wave0 for A, wave4 for B): 2 outputs/lane
    const int e_b0 = L >> 4;
    const int e_j  = L & 15;
    const int e_cg = e_j >> 3;
    const int e_s0 = e_b0 * 8 + (e_j & 7);
    const int e_s1 = e_s0 + 32;
    const int bglob0 = bg * 8 + e_b0;
    const int bglob1 = bglob0 + 4;
    const int e_col  = c0wg + e_j;

    float4* h4 = (float4*)h_buf;
    float4* g4 = (float4*)g_buf;

    float creg0 = 0.f, creg1 = 0.f;       // live in wave4
    __syncthreads();   // weights ready

    for (int t = 0; t < 512; ++t) {
        const unsigned tu = (unsigned)t;
        float v[64];

        // ================= phase A =================
        float xb0 = 0.f, xb1 = 0.f;
        if (w == 0) {   // xb prefetch (uncached; 1 RTT, hidden under w7's poll)
            ld_uc2(XBH + ((size_t)bglob0 * 512 + t) * 1024 + e_col,
                   XBH + ((size_t)bglob1 * 512 + t) * 1024 + e_col, xb0, xb1);
        }
        if (w == 7) spin_tags64(tagH, L, tu);
        __syncthreads();                  // S1: h(t-1) of all slices published
        {
            const float4* hb = h4 + ((t + 1) & 1) * 8192 + bg * 2048;
            float4 s0 = ld_uc4_nw(hb + 4 * tid + 0);
            float4 s1 = ld_uc4_nw(hb + 4 * tid + 1);
            float4 s2 = ld_uc4_nw(hb + 4 * tid + 2);
            float4 s3 = ld_uc4_nw(hb + 4 * tid + 3);
            asm volatile("s_waitcnt vmcnt(0)" ::: "memory");
            __builtin_amdgcn_sched_barrier(0);
            hg4[4 * tid + 0] = s0; hg4[4 * tid + 1] = s1;
            hg4[4 * tid + 2] = s2; hg4[4 * tid + 3] = s3;
        }
        __syncthreads();                  // S2: staged
        {
            float4 hv[8], av[8];
#pragma unroll
            for (int r = 0; r < 8; ++r) hv[r] = hg4[hIdx[r]];
#pragma unroll
            for (int c = 0; c < 8; ++c) av[c] = a_l4[aIdx[c]];
#pragma unroll
            for (int r = 0; r < 8; ++r)
#pragma unroll
                for (int c = 0; c < 8; ++c)
                    v[r * 8 + c] = hv[r].x * av[c].x + hv[r].y * av[c].y
                                 + hv[r].z * av[c].z + hv[r].w * av[c].w;
        }
#pragma unroll
        for (int j = 0; j < 32; ++j) v[j] = v[2 * j] + __shfl_xor(v[2 * j + 1], 1);
#pragma unroll
        for (int j = 0; j < 16; ++j) v[j] = v[2 * j] + __shfl_xor(v[2 * j + 1], 2);
#pragma unroll
        for (int j = 0; j < 8; ++j)  v[j] = v[2 * j] + __shfl_xor(v[2 * j + 1], 4);
#pragma unroll
        for (int j = 0; j < 4; ++j)  v[j] = v[2 * j] + __shfl_xor(v[2 * j + 1], 8);
#pragma unroll
        for (int j = 0; j < 2; ++j)  v[j] = v[2 * j] + __shfl_xor(v[2 * j + 1], 16);
        v[0] = v[0] + __shfl_xor(v[1], 32);
        __syncthreads();                  // S3a: all hg reads complete (scr aliases hg)
        scr[w * 64 + L] = v[0];
        __syncthreads();                  // S3b
        if (w == 0) {                     // epilogue A: g = (h@A)*xb, publish tagG
            float sA0 = 0.f, sA1 = 0.f;
#pragma unroll
            for (int k2 = 0; k2 < 4; ++k2) {
                sA0 += scr[(k2 * 2 + e_cg) * 64 + e_s0];
                sA1 += scr[(k2 * 2 + e_cg) * 64 + e_s1];
            }
            float* gw = g_buf + (t & 1) * 32768;
            st_uc(gw + (size_t)bglob0 * 1024 + e_col, sA0 * xb0);
            st_uc(gw + (size_t)bglob1 * 1024 + e_col, sA1 * xb1);
            asm volatile("s_waitcnt vmcnt(0)" ::: "memory");
            if (L == 0) st_uc_u(tagG + sg, tu + 1u);
        }

        // ================= phase B =================
        if (w == 7) spin_tags64(tagG, L, tu + 1u);
        __syncthreads();                  // S1': g(t) of all slices published
        {
            const float4* gb = g4 + (t & 1) * 8192 + bg * 2048;
            float4 s0 = ld_uc4_nw(gb + 4 * tid + 0);
            float4 s1 = ld_uc4_nw(gb + 4 * tid + 1);
            float4 s2 = ld_uc4_nw(gb + 4 * tid + 2);
            float4 s3 = ld_uc4_nw(gb + 4 * tid + 3);
            asm volatile("s_waitcnt vmcnt(0)" ::: "memory");
            __builtin_amdgcn_sched_barrier(0);
            hg4[4 * tid + 0] = s0; hg4[4 * tid + 1] = s1;
            hg4[4 * tid + 2] = s2; hg4[4 * tid + 3] = s3;
        }
        __syncthreads();                  // S2'
        {
            float4 gv[8], cv[8];
#pragma unroll
            for (int r = 0; r < 8; ++r) gv[r] = hg4[hIdx[r]];
#pragma unroll
            for (int c = 0; c < 8; ++c) cv[c] = ct_l4[aIdx[c]];
#pragma unroll
            for (int r = 0; r < 8; ++r)
#pragma unroll
                for (int c = 0; c < 8; ++c)
                    v[r * 8 + c] = gv[r].x * cv[c].x + gv[r].y * cv[c].y
                                 + gv[r].z * cv[c].z + gv[r].w * cv[c].w;
        }
#pragma unroll
        for (int j = 0; j < 32; ++j) v[j] = v[2 * j] + __shfl_xor(v[2 * j + 1], 1);
#pragma unroll
        for (int j = 0; j < 16; ++j) v[j] = v[2 * j] + __shfl_xor(v[2 * j + 1], 2);
#pragma unroll
        for (int j = 0; j < 8; ++j)  v[j] = v[2 * j] + __shfl_xor(v[2 * j + 1], 4);
#pragma unroll
        for (int j = 0; j < 4; ++j)  v[j] = v[2 * j] + __shfl_xor(v[2 * j + 1], 8);
#pragma unroll
        for (int j = 0; j < 2; ++j)  v[j] = v[2 * j] + __shfl_xor(v[2 * j + 1], 16);
        v[0] = v[0] + __shfl_xor(v[1], 32);
        __syncthreads();                  // S3a'
        scr[w * 64 + L] = v[0];
        __syncthreads();                  // S3b'
        if (w == 4) {                     // epilogue B: gates + cell, publish tagH
            float pf0 = scr[(0 + e_cg) * 64 + e_s0], pi0 = scr[(2 + e_cg) * 64 + e_s0];
            float pg0 = scr[(4 + e_cg) * 64 + e_s0], po0 = scr[(6 + e_cg) * 64 + e_s0];
            float pf1 = scr[(0 + e_cg) * 64 + e_s1], pi1 = scr[(2 + e_cg) * 64 + e_s1];
            float pg1 = scr[(4 + e_cg) * 64 + e_s1], po1 = scr[(6 + e_cg) * 64 + e_s1];
            float ft = 1.f / (1.f + __expf(-pf0));
            float it = 1.f / (1.f + __expf(-pi0));
            float gt = tanhf(pg0);
            float ot = 1.f / (1.f + __expf(-po0));
            creg0 = ft * creg0 + it * gt;
            float hv0 = ot * tanhf(creg0);
            ft = 1.f / (1.f + __expf(-pf1));
            it = 1.f / (1.f + __expf(-pi1));
            gt = tanhf(pg1);
            ot = 1.f / (1.f + __expf(-po1));
            creg1 = ft * creg1 + it * gt;
            float hv1 = ot * tanhf(creg1);
            float* hw = h_buf + (t & 1) * 32768;
            st_uc(hw + (size_t)bglob0 * 1024 + e_col, hv0);
            st_uc(hw + (size_t)bglob1 * 1024 + e_col, hv1);
            st_uc(XBH + ((size_t)bglob0 * 512 + t) * 1024 + e_col, hv0);
            st_uc(XBH + ((size_t)bglob1 * 512 + t) * 1024 + e_col, hv1);
            if (t == 511) {
                st_uc(ht_out + (size_t)bglob0 * 1024 + e_col, hv0);
                st_uc(ht_out + (size_t)bglob1 * 1024 + e_col, hv1);
                st_uc(ct_out + (size_t)bglob0 * 1024 + e_col, creg0);
                st_uc(ct_out + (size_t)bglob1 * 1024 + e_col, creg1);
            }
            asm volatile("s_waitcnt vmcnt(0)" ::: "memory");
            if (L == 0) st_uc_u(tagH + sg, tu + 1u);
        }
    }
}

// ---------------------------------------------------------------- launch
extern "C" void kernel_launch(void* const* d_in, const int* in_sizes, int n_in,
                              void* d_out, int out_size, void* d_ws, size_t ws_size,
                              hipStream_t stream) {
    const float* X   = (const float*)d_in[0];
    const float* A   = (const float*)d_in[1];
    const float* Bw  = (const float*)d_in[2];
    const float* CTm = (const float*)d_in[3];

    float* out    = (float*)d_out;
    float* XBH    = out;                                  // xb in, hidden_seq out
    float* ht_out = out + (size_t)32 * 512 * 1024;
    float* ct_out = ht_out + 32 * 1024;

    float* h_buf = (float*)d_ws;                          // 2 x 32768 floats
    float* g_buf = h_buf + 65536;                         // 2 x 32768 floats
    unsigned* tags = (unsigned*)(g_buf + 65536);          // 4 x 128 uints

    (void)hipFuncSetAttribute((const void*)scan_kernel,
                              hipFuncAttributeMaxDynamicSharedMemorySize, 163840);

    init_kernel<<<dim3(256), dim3(256), 0, stream>>>(h_buf, tags);
    xb_gemm<<<dim3(1024), dim3(256), 0, stream>>>(X, Bw, XBH);
    scan_kernel<<<dim3(256), dim3(NTHR), 163840, stream>>>(A, CTm, XBH, h_buf, g_buf,
                                                           ht_out, ct_out, tags);
}

// Round 8
// 4867.883 us; speedup vs baseline: 1.5016x; 1.5016x over previous
//
#include <hip/hip_runtime.h>
#include <math.h>

#define NTHR 512

// ---------------------------------------------------------------- uncached ops
__device__ __forceinline__ void st_uc(float* p, float v) {
    asm volatile("global_store_dword %0, %1, off sc0 sc1" :: "v"(p), "v"(v) : "memory");
}
__device__ __forceinline__ void st_uc_u(unsigned* p, unsigned v) {
    asm volatile("global_store_dword %0, %1, off sc0 sc1" :: "v"(p), "v"(v) : "memory");
}
__device__ __forceinline__ float4 ld_uc4_nw(const float4* p) {   // no wait
    float4 v;
    asm volatile("global_load_dwordx4 %0, %1, off sc0 sc1" : "=v"(v) : "v"(p) : "memory");
    return v;
}
__device__ __forceinline__ float ld_uc_nw(const float* p) {      // no wait
    float v;
    asm volatile("global_load_dword %0, %1, off sc0 sc1" : "=v"(v) : "v"(p) : "memory");
    return v;
}
// one wave polls 64 slice tags (lanes 0..63 <-> tags, 4 cache lines)
__device__ __forceinline__ void spin_tags64(const unsigned* base, int L, unsigned target) {
    const unsigned* p = base + L;
    for (;;) {
        unsigned v;
        asm volatile("global_load_dword %0, %1, off sc0 sc1\n\ts_waitcnt vmcnt(0)"
                     : "=v"(v) : "v"(p) : "memory");
        if (!__any((int)(v < target))) return;
        __builtin_amdgcn_s_sleep(1);
    }
}

// ---------------------------------------------------------------- init
// h_buf: 2 slots x 32768 floats (zeroed = h(-1)); tags: 8 bg x {H:64, G:64}.
__global__ void init_kernel(float* h_buf, unsigned* tags) {
    int i = blockIdx.x * blockDim.x + threadIdx.x;
    if (i < 65536) st_uc(h_buf + i, 0.0f);
    if (i < 1024) st_uc_u(tags + i, 0u);
}

// ---------------------------------------------------------------- xb = x @ b
__global__ __launch_bounds__(256) void xb_gemm(const float* __restrict__ X,
                                               const float* __restrict__ Bw,
                                               float* __restrict__ XB) {
    __shared__ float xs[16][132];
    __shared__ float bs[16][132];
    const int bm = blockIdx.x >> 3;
    const int bn = blockIdx.x & 7;
    const int m0 = bm * 128, n0 = bn * 128;
    const int tid = threadIdx.x;
    const int tx = tid & 15, ty = tid >> 4;
    float acc[8][8];
#pragma unroll
    for (int i = 0; i < 8; ++i)
#pragma unroll
        for (int j = 0; j < 8; ++j) acc[i][j] = 0.f;

    for (int k0 = 0; k0 < 1024; k0 += 16) {
#pragma unroll
        for (int p = 0; p < 2; ++p) {
            int f = tid + p * 256;
            int m = f >> 2, kq = f & 3;
            float4 v = *(const float4*)&X[(size_t)(m0 + m) * 1024 + k0 + kq * 4];
            xs[kq * 4 + 0][m] = v.x; xs[kq * 4 + 1][m] = v.y;
            xs[kq * 4 + 2][m] = v.z; xs[kq * 4 + 3][m] = v.w;
        }
#pragma unroll
        for (int p = 0; p < 2; ++p) {
            int f = tid + p * 256;
            int k = f >> 5, n = (f & 31) * 4;
            float4 v = *(const float4*)&Bw[(size_t)(k0 + k) * 1024 + n0 + n];
            *(float4*)&bs[k][n] = v;
        }
        __syncthreads();
#pragma unroll
        for (int k = 0; k < 16; ++k) {
            float xv[8], bv[8];
            *(float4*)&xv[0] = *(const float4*)&xs[k][ty * 8];
            *(float4*)&xv[4] = *(const float4*)&xs[k][ty * 8 + 4];
            *(float4*)&bv[0] = *(const float4*)&bs[k][tx * 8];
            *(float4*)&bv[4] = *(const float4*)&bs[k][tx * 8 + 4];
#pragma unroll
            for (int i = 0; i < 8; ++i)
#pragma unroll
                for (int j = 0; j < 8; ++j) acc[i][j] += xv[i] * bv[j];
        }
        __syncthreads();
    }
#pragma unroll
    for (int i = 0; i < 8; ++i)
#pragma unroll
        for (int j = 0; j < 8; j += 4) {
            float4 v = make_float4(acc[i][j], acc[i][j + 1], acc[i][j + 2], acc[i][j + 3]);
            *(float4*)&XB[(size_t)(m0 + ty * 8 + i) * 1024 + n0 + tx * 8 + j] = v;
        }
}

// ---------------------------------------------------------------- persistent scan
// 256 WGs; each runs TWO independent streams: (bg0=wg>>6, sg=wg&63) and
// (bg1=bg0+4, sg). 8 batch-groups of 4 batches; slice = 16 cols. Per step 4
// sub-phases S0.A, S1.A, S0.B, S1.B — every tag dependency has one sub-phase
// of other-stream work between publish and detect (latency hiding).
// Tag protocol (r4-r7, proven): per-slice monotonic tags, depth-2 ping-pong.
__global__ __launch_bounds__(NTHR, 1) void scan_kernel(
    const float* __restrict__ A, const float* __restrict__ CTm,
    float* __restrict__ XBH, float* __restrict__ h_buf, float* __restrict__ g_buf,
    float* __restrict__ ht_out, float* __restrict__ ct_out, unsigned* __restrict__ tags) {
    extern __shared__ float lds[];
    float* a_lf  = lds;                    // [16 cols][1024] col-major (64KB)
    float* ct_lf = lds + 16384;            // (64KB)
    float* st0f  = lds + 32768;            // stream0 staging 4096 floats (16KB)
    float* st1f  = lds + 36864;            // stream1 staging (16KB)
    float4* lds4  = (float4*)lds;
    const float4* a_l4  = lds4;
    const float4* ct_l4 = lds4 + 4096;
    float4* st0_4 = lds4 + 8192;
    float4* st1_4 = lds4 + 9216;
    float* scr0 = st0f;                    // 256 floats, aliases staging (sync-guarded)
    float* scr1 = st1f;

    const int wg = blockIdx.x;
    const int bg0 = wg >> 6;               // 0..3
    const int bg1 = bg0 + 4;               // 4..7
    const int sg = wg & 63;
    const int c0wg = sg * 16;
    const int tid = threadIdx.x;

    // ---- one-time weight preload: cols c0wg..c0wg+15, col-major ----
    {
        const int c = tid & 15, i0 = tid >> 4;
        for (int i = i0; i < 1024; i += 32) {
            a_lf[c * 1024 + i]  = A[(size_t)i * 1024 + c0wg + c];
            ct_lf[c * 1024 + i] = CTm[(size_t)i * 1024 + c0wg + c];
        }
    }

    const int L  = tid & 63;
    const int w  = tid >> 6;
    const int Lc = L & 7;
    const int Lb = (L >> 3) & 3;
    const int cg = w & 1, kq = w >> 1;     // col half, k-quarter (== gate in phase B)

    int wIdx[8], sIdx[4];
#pragma unroll
    for (int c = 0; c < 8; ++c) wIdx[c] = (cg * 8 + (c ^ Lc)) * 256 + kq * 64 + L;
#pragma unroll
    for (int r = 0; r < 4; ++r) sIdx[r] = ((r ^ Lb) << 8) + kq * 64 + L;

    // epilogue lane mapping (w0 = stream0 epis, w4 = stream1 epis): 1 output/lane
    const int e_b   = L >> 4;              // 0..3 local batch
    const int e_j   = L & 15;              // col within slice
    const int e_cgo = e_j >> 3;
    const int e_sx  = e_b * 8 + (e_j & 7);
    const int col   = c0wg + e_j;

    float4* h4 = (float4*)h_buf;
    float4* g4 = (float4*)g_buf;

    float creg = 0.f;                      // cell state: w0 lanes (stream0), w4 lanes (stream1)
    __syncthreads();                       // weights ready

    // generic sub-phase. All-wave syncs are unconditional.
    auto sub = [&](int t, const unsigned* pollbase, unsigned polltgt,
                   const float4* src4, float4* st4, float* scr,
                   const float4* wmat, int epiw, bool isA, int bgx, float xbv) {
        if (w == 7) spin_tags64(pollbase, L, polltgt);
        __syncthreads();                   // S1: producer data visible at LLC
        {                                  // stage 16KB, coalesced, stride-16B LDS
            float4 u0 = ld_uc4_nw(src4 + tid);
            float4 u1 = ld_uc4_nw(src4 + 512 + tid);
            asm volatile("s_waitcnt vmcnt(0)" ::: "memory");
            __builtin_amdgcn_sched_barrier(0);
            st4[tid] = u0; st4[512 + tid] = u1;
        }
        __syncthreads();                   // S2: staged
        float v[32];
        {
            float4 sv[4], wv[8];
#pragma unroll
            for (int r = 0; r < 4; ++r) sv[r] = st4[sIdx[r]];
#pragma unroll
            for (int c = 0; c < 8; ++c) wv[c] = wmat[wIdx[c]];
#pragma unroll
            for (int r = 0; r < 4; ++r)
#pragma unroll
                for (int c = 0; c < 8; ++c)
                    v[r * 8 + c] = sv[r].x * wv[c].x + sv[r].y * wv[c].y
                                 + sv[r].z * wv[c].z + sv[r].w * wv[c].w;
        }
#pragma unroll
        for (int j = 0; j < 16; ++j) v[j] = v[2 * j] + __shfl_xor(v[2 * j + 1], 1);
#pragma unroll
        for (int j = 0; j < 8; ++j)  v[j] = v[2 * j] + __shfl_xor(v[2 * j + 1], 2);
#pragma unroll
        for (int j = 0; j < 4; ++j)  v[j] = v[2 * j] + __shfl_xor(v[2 * j + 1], 4);
#pragma unroll
        for (int j = 0; j < 2; ++j)  v[j] = v[2 * j] + __shfl_xor(v[2 * j + 1], 8);
        v[0] = v[0] + __shfl_xor(v[1], 16);
        v[0] = v[0] + __shfl_xor(v[0], 32);   // merge k-halves (lanes 0-31 vs 32-63)
        __syncthreads();                   // S3: all staging reads done (scr aliases)
        if (L < 32) scr[kq * 64 + cg * 32 + L] = v[0];
        __syncthreads();                   // S4
        if (w == epiw) {
            asm volatile("s_waitcnt vmcnt(0)" ::: "memory");   // xb prefetch ready
            const int bglob = bgx * 4 + e_b;
            float q0 = scr[e_cgo * 32 + e_sx];
            float q1 = scr[64 + e_cgo * 32 + e_sx];
            float q2 = scr[128 + e_cgo * 32 + e_sx];
            float q3 = scr[192 + e_cgo * 32 + e_sx];
            if (isA) {
                float gv = (q0 + q1 + q2 + q3) * xbv;
                st_uc(g_buf + (t & 1) * 32768 + (size_t)bglob * 1024 + col, gv);
                asm volatile("s_waitcnt vmcnt(0)" ::: "memory");
                if (L == 0) st_uc_u(tags + bgx * 128 + 64 + sg, (unsigned)t + 1u);
            } else {
                float ft = 1.f / (1.f + __expf(-q0));
                float it = 1.f / (1.f + __expf(-q1));
                float gt = tanhf(q2);
                float ot = 1.f / (1.f + __expf(-q3));
                creg = ft * creg + it * gt;
                float hv = ot * tanhf(creg);
                st_uc(h_buf + (t & 1) * 32768 + (size_t)bglob * 1024 + col, hv);
                st_uc(XBH + ((size_t)bglob * 512 + t) * 1024 + col, hv);
                if (t == 511) {
                    st_uc(ht_out + (size_t)bglob * 1024 + col, hv);
                    st_uc(ct_out + (size_t)bglob * 1024 + col, creg);
                }
                asm volatile("s_waitcnt vmcnt(0)" ::: "memory");
                if (L == 0) st_uc_u(tags + bgx * 128 + sg, (unsigned)t + 1u);
            }
        }
    };

    for (int t = 0; t < 512; ++t) {
        const unsigned tu = (unsigned)t;
        // xb prefetch for both streams' A-epilogues (no wait; drained later)
        float xb0 = 0.f, xb1 = 0.f;
        if (w == 0) xb0 = ld_uc_nw(XBH + ((size_t)(bg0 * 4 + e_b) * 512 + t) * 1024 + col);
        if (w == 4) xb1 = ld_uc_nw(XBH + ((size_t)(bg1 * 4 + e_b) * 512 + t) * 1024 + col);

        // SUB0: stream0 phase A  (reads h(t-1) slot (t+1)&1)
        sub(t, tags + bg0 * 128, tu,
            h4 + ((t + 1) & 1) * 8192 + bg0 * 1024, st0_4, scr0, a_l4, 0, true, bg0, xb0);
        // SUB1: stream1 phase A
        sub(t, tags + bg1 * 128, tu,
            h4 + ((t + 1) & 1) * 8192 + bg1 * 1024, st1_4, scr1, a_l4, 4, true, bg1, xb1);
        // SUB2: stream0 phase B  (reads g(t) slot t&1)
        sub(t, tags + bg0 * 128 + 64, tu + 1u,
            g4 + (t & 1) * 8192 + bg0 * 1024, st0_4, scr0, ct_l4, 0, false, bg0, 0.f);
        // SUB3: stream1 phase B
        sub(t, tags + bg1 * 128 + 64, tu + 1u,
            g4 + (t & 1) * 8192 + bg1 * 1024, st1_4, scr1, ct_l4, 4, false, bg1, 0.f);
    }
}

// ---------------------------------------------------------------- launch
extern "C" void kernel_launch(void* const* d_in, const int* in_sizes, int n_in,
                              void* d_out, int out_size, void* d_ws, size_t ws_size,
                              hipStream_t stream) {
    const float* X   = (const float*)d_in[0];
    const float* A   = (const float*)d_in[1];
    const float* Bw  = (const float*)d_in[2];
    const float* CTm = (const float*)d_in[3];

    float* out    = (float*)d_out;
    float* XBH    = out;                                  // xb in, hidden_seq out
    float* ht_out = out + (size_t)32 * 512 * 1024;
    float* ct_out = ht_out + 32 * 1024;

    float* h_buf = (float*)d_ws;                          // 2 x 32768 floats
    float* g_buf = h_buf + 65536;                         // 2 x 32768 floats
    unsigned* tags = (unsigned*)(g_buf + 65536);          // 8 bg x 128 uints

    (void)hipFuncSetAttribute((const void*)scan_kernel,
                              hipFuncAttributeMaxDynamicSharedMemorySize, 163840);

    init_kernel<<<dim3(256), dim3(256), 0, stream>>>(h_buf, tags);
    xb_gemm<<<dim3(1024), dim3(256), 0, stream>>>(X, Bw, XBH);
    scan_kernel<<<dim3(256), dim3(NTHR), 163840, stream>>>(A, CTm, XBH, h_buf, g_buf,
                                                           ht_out, ct_out, tags);
}